// Round 7
// baseline (5695.621 us; speedup 1.0000x reference)
//
#include <hip/hip_runtime.h>

#define NB 1024
#define SL 300
#define NT 150
#define NH 256
#define LA 320
#define NV 81
#define HST 272   // LDS row stride in halves: 136 words ≡ 8 (mod 32) -> conflict-free MFMA A-reads

typedef _Float16 f16;
typedef _Float16 f16x2 __attribute__((ext_vector_type(2)));
typedef _Float16 f16x8 __attribute__((ext_vector_type(8)));
typedef float    f32x4 __attribute__((ext_vector_type(4)));

// ws float offsets
#define OFF_WATT    0u         // [512][320] f32 W_att^T (setup intermediate)
#define OFF_WCOMBT  163840u    // [512][256] f32 W_comb^T (intermediate)
#define OFF_P1B     294912u    // [81][320]  f32 emb@W_att[:,:256]^T + b_att
#define OFF_P2B     320832u    // [81][256]  f32 emb@W_comb[:,:256]^T + b_comb
#define OFF_Q2T     341568u    // [81][256]  f32 (intermediate)
#define OFF_Q2PE    362304u    // [256]
#define OFF_PE      362560u    // [256]
#define OFF_Q2TP    362816u    // [21][1024] f32 4v-panel Q2T
#define OFF_WCATM   384320u    // f16 MFMA-frag gates weights [64 nt][16 kw][64 lane][8]
#define OFF_WATTM   646464u    // f16 MFMA-frag attn-h weights [20 nt][8 kw][64 lane][8]
#define OFF_WFCPH   687424u    // f16 [32][81][8] W_fc^T (dot2 layout)
#define OFF_LOSS    697792u    // [1024]
#define OFF_XEX     698816u    // f16 [1024][256] x exchange
#define OFF_HEX     829888u    // f16 [1024][256] h exchange
#define OFF_FLAG    960960u    // int [2][32][8][16] step-counter flags (64B spaced)

static __device__ __forceinline__ float rcpf(float x)  { return __builtin_amdgcn_rcpf(x); }
static __device__ __forceinline__ float sigm(float x)  { return rcpf(1.f + __expf(-x)); }
static __device__ __forceinline__ float tanhf_(float x){ return 1.f - 2.f * rcpf(1.f + __expf(2.f * x)); }

static __device__ __forceinline__ float dot2(f16x2 a, f16x2 b, float c) {
#if __has_builtin(__builtin_amdgcn_fdot2)
    return __builtin_amdgcn_fdot2(a, b, c, false);
#else
    return c + (float)a[0] * (float)b[0] + (float)a[1] * (float)b[1];
#endif
}
#define DOT4(wf4, af4, acc) { \
    acc = dot2(__builtin_bit_cast(f16x2, (wf4).x), __builtin_bit_cast(f16x2, (af4).x), acc); \
    acc = dot2(__builtin_bit_cast(f16x2, (wf4).y), __builtin_bit_cast(f16x2, (af4).y), acc); \
    acc = dot2(__builtin_bit_cast(f16x2, (wf4).z), __builtin_bit_cast(f16x2, (af4).z), acc); \
    acc = dot2(__builtin_bit_cast(f16x2, (wf4).w), __builtin_bit_cast(f16x2, (af4).w), acc); }

// ---------------- setup kernels (unchanged layouts) ----------------
__global__ __launch_bounds__(128) void k_pe(float* __restrict__ pe) {
    const int i = threadIdx.x;
    const float arg  = (float)(2 * i) * (-0.035977892078031968f);
    const float divf = expf(arg) * 300.0f;
    pe[2 * i]     = (float)sin((double)divf);
    pe[2 * i + 1] = (float)cos((double)divf);
}
__global__ __launch_bounds__(256) void k_tr_att(const float* __restrict__ W, float* __restrict__ WT) {
    const int i = blockIdx.x * 256 + threadIdx.x;
    if (i < 512 * LA) { const int k = i / LA, l = i - k * LA; WT[i] = W[l * 512 + k]; }
}
__global__ __launch_bounds__(256) void k_tr_comb(const float* __restrict__ W, float* __restrict__ WT) {
    const int i = blockIdx.x * 256 + threadIdx.x;
    const int k = i >> 8, j = i & 255;
    if (i < 512 * NH) WT[i] = W[j * 512 + k];
}
__global__ __launch_bounds__(320) void k_p1b(const float* __restrict__ emb, const float* __restrict__ WATT,
                                             const float* __restrict__ b_att, float* __restrict__ P1B) {
    __shared__ float e[NH];
    const int v = blockIdx.x, tid = threadIdx.x;
    if (tid < NH) e[tid] = emb[v * NH + tid];
    __syncthreads();
    float a = b_att[tid];
    #pragma unroll 8
    for (int k = 0; k < NH; ++k) a += e[k] * WATT[k * LA + tid];
    P1B[v * LA + tid] = a;
}
__global__ __launch_bounds__(256) void k_p2q(const float* __restrict__ emb, const float* __restrict__ WCOMBT,
                                             const float* __restrict__ b_comb,
                                             float* __restrict__ P2B, float* __restrict__ Q2T) {
    __shared__ float e[NH];
    const int v = blockIdx.x, tid = threadIdx.x;
    e[tid] = emb[v * NH + tid];
    __syncthreads();
    float a = b_comb[tid], q = 0.f;
    #pragma unroll 8
    for (int k = 0; k < NH; ++k) {
        a += e[k] * WCOMBT[k * NH + tid];
        q += e[k] * WCOMBT[(NH + k) * NH + tid];
    }
    P2B[v * NH + tid] = a;
    Q2T[v * NH + tid] = q;
}
__global__ __launch_bounds__(256) void k_q2pe(const float* __restrict__ pe, const float* __restrict__ WCOMBT,
                                              float* __restrict__ Q2PE) {
    __shared__ float e[NH];
    const int tid = threadIdx.x;
    e[tid] = pe[tid];
    __syncthreads();
    float q = 0.f;
    #pragma unroll 8
    for (int k = 0; k < NH; ++k) q += e[k] * WCOMBT[(NH + k) * NH + tid];
    Q2PE[tid] = q;
}
__global__ __launch_bounds__(256) void k_pan_q2(const float* __restrict__ Q2T, float* __restrict__ P) {
    const int i = blockIdx.x * 256 + threadIdx.x;
    if (i < NV * NH) {
        const int v = i >> 8, j = i & 255;
        P[(v >> 2) * 1024 + j * 4 + (v & 3)] = Q2T[v * NH + j];
    }
}
__global__ __launch_bounds__(256) void k_pan_cat_m(const float* __restrict__ Wih, const float* __restrict__ Whh,
                                                   f16* __restrict__ P) {
    const int i = blockIdx.x * 256 + threadIdx.x;
    if (i < 512 * 1024) {
        const int k = i >> 10, c = i & 1023, jcol = c >> 2, g = c & 3;
        const float v = (k < NH) ? Wih[(g * NH + jcol) * NH + k] : Whh[(g * NH + jcol) * NH + (k - NH)];
        const int nt = c >> 4, kw = k >> 5, kr = k & 31;
        const int l = (kr >> 3) * 16 + (c & 15), jj = kr & 7;
        P[nt * 8192 + kw * 512 + l * 8 + jj] = (f16)v;
    }
}
__global__ __launch_bounds__(256) void k_pan_att_m(const float* __restrict__ W, f16* __restrict__ P) {
    const int i = blockIdx.x * 256 + threadIdx.x;
    if (i < 256 * LA) {
        const int k = i / LA, lcol = i - k * LA;
        const float v = W[lcol * 512 + 256 + k];
        const int nt = lcol >> 4, kw = k >> 5, kr = k & 31;
        const int l = (kr >> 3) * 16 + (lcol & 15), jj = kr & 7;
        P[nt * 4096 + kw * 512 + l * 8 + jj] = (f16)v;
    }
}
__global__ __launch_bounds__(256) void k_pan_fc_h(const float* __restrict__ W, f16* __restrict__ P) {
    const int i = blockIdx.x * 256 + threadIdx.x;
    if (i < 256 * NV) {
        const int k = i / NV, v = i - k * NV;
        P[(k >> 3) * 648 + v * 8 + (k & 7)] = (f16)W[v * NH + k];
    }
}
__global__ __launch_bounds__(256) void k_zero(int* __restrict__ p) {
    p[blockIdx.x * 256 + threadIdx.x] = 0;
}

// ---------------- persistent decoder: 256 blocks = 32 row-groups x 8 col-slices ----------------
__global__ __launch_bounds__(1024, 4) void k_run(
    const int* __restrict__ enc, const int* __restrict__ tgt,
    const f16* __restrict__ WATTM, const float* __restrict__ P1B,
    const float* __restrict__ P2B, const float* __restrict__ Q2TP,
    const float* __restrict__ Q2PE, const f16* __restrict__ WCATM,
    const f16* __restrict__ WFCPH,
    const float* __restrict__ bih, const float* __restrict__ bhh,
    const float* __restrict__ bfc, f16* __restrict__ xex, f16* __restrict__ hex,
    int* __restrict__ flagx, int* __restrict__ flagh,
    float* __restrict__ out_logits, float* __restrict__ loss_out)
{
    __shared__ __attribute__((aligned(16))) f16 hbufh[32][HST]; // h(t-1) for all 32 group rows
    __shared__ __attribute__((aligned(16))) f16 xh[32][HST];    // x(t) for all 32 group rows
    __shared__ float p_s[4][324];        // home rows: raw z then exp
    __shared__ float gex[32][132];       // gates output: [group row][local gate-col]
    __shared__ float bsum_lds[128];      // bias for my 128 gate-cols
    __shared__ float cw_s[4][84];
    __shared__ float lg_s[4][84];
    __shared__ float lgpart[2][4][84];
    __shared__ unsigned short idx16[4][SL];
    __shared__ unsigned short cnt16[4][NV];
    __shared__ unsigned short offs16[4][NV + 1];
    __shared__ float redM[4][4];
    __shared__ float redS[4][4][2];
    __shared__ float bfc_s[84];
    __shared__ float loss_s[4];
    __shared__ int   xd_s[4];

    const int tid  = threadIdx.x;
    const int r4   = tid & 3;
    const int q4   = tid >> 2;
    const int rowg = tid >> 8;
    const int jg   = tid & 255;
    const int wid  = tid >> 6;
    const int lane = tid & 63;
    const int mrow = lane & 15;
    const int arow4 = mrow & 3;
    const int khi  = lane >> 4;

    const int rg   = blockIdx.x & 31;    // row group: rows [rg*32, rg*32+32)
    const int cs   = blockIdx.x >> 5;    // col slice: gate-cols [cs*128, cs*128+128)
    const int rbase = rg * 32;           // first group row (global)
    const int home0 = cs * 4;            // my home rows within group = home0..home0+3
    const int grow0 = rbase + home0;     // global index of home row 0
    int* __restrict__ fx = flagx + rg * 128;   // [8 partners][16-int spacing]
    int* __restrict__ fh = flagh + rg * 128;

    // ---- init ----
    for (int i = tid; i < 32 * HST; i += 1024) { hbufh[i / HST][i % HST] = (f16)0.f; }
    if (tid < 128) {
        const int cg = cs * 128 + tid, j = cg >> 2, g = cg & 3;
        bsum_lds[tid] = bih[g * NH + j] + bhh[g * NH + j];
    }
    if (tid < 84) bfc_s[tid] = (tid < NV) ? bfc[tid] : 0.f;
    if (tid < 4) { xd_s[tid] = 1; loss_s[tid] = 0.f; }
    const int* __restrict__ encr = enc + (grow0 + rowg) * SL;
    if (jg < NV) {
        int c = 0;
        for (int l = 0; l < SL; ++l) c += (encr[l] == jg);
        cnt16[rowg][jg] = (unsigned short)c;
    }
    __syncthreads();
    if (jg == 0) {
        int o = 0; offs16[rowg][0] = 0;
        for (int v = 0; v < NV; ++v) { o += cnt16[rowg][v]; offs16[rowg][v + 1] = (unsigned short)o; }
    }
    __syncthreads();
    if (jg < NV) {
        int o = offs16[rowg][jg];
        for (int l = 0; l < SL; ++l) if (encr[l] == jg) idx16[rowg][o++] = (unsigned short)l;
    }
    __syncthreads();

    float creg = 0.f;   // cell state for (group row tid>>5, unit cs*32 + (tid&31))

    for (int t = 0; t < NT; ++t) {
        // ---- phase 1: attention z for home rows via MFMA ----
        {
            f32x4 za0 = {0.f, 0.f, 0.f, 0.f}, za1 = {0.f, 0.f, 0.f, 0.f};
            const bool two = (wid < 4);
            const f16* __restrict__ B0 = WATTM + wid * 4096 + lane * 8;
            const f16* __restrict__ B1 = WATTM + (16 + wid) * 4096 + lane * 8;
            const f16* __restrict__ hr = &hbufh[home0 + arow4][khi * 8];
            #pragma unroll 4
            for (int kw = 0; kw < 8; ++kw) {
                const f16x8 a = *(const f16x8*)(hr + kw * 32);
                const f16x8 b0 = *(const f16x8*)(B0 + kw * 512);
                za0 = __builtin_amdgcn_mfma_f32_16x16x32_f16(a, b0, za0, 0, 0, 0);
                if (two) {
                    const f16x8 b1 = *(const f16x8*)(B1 + kw * 512);
                    za1 = __builtin_amdgcn_mfma_f32_16x16x32_f16(a, b1, za1, 0, 0, 0);
                }
            }
            if (lane < 16) {
                #pragma unroll
                for (int i = 0; i < 4; ++i) p_s[i][wid * 16 + mrow] = za0[i];
                if (two) {
                    #pragma unroll
                    for (int i = 0; i < 4; ++i) p_s[i][256 + wid * 16 + mrow] = za1[i];
                }
            }
        }
        __syncthreads();                                   // B1

        // ---- softmax stats (adds P1B) ----
        {
            const float* __restrict__ P1r = P1B + xd_s[rowg] * LA;
            const float za = p_s[rowg][jg] + P1r[jg];
            const float zb = (jg < 64) ? (p_s[rowg][256 + jg] + P1r[256 + jg]) : -3.4e38f;
            float m = fmaxf(za, zb);
            #pragma unroll
            for (int off = 32; off > 0; off >>= 1) m = fmaxf(m, __shfl_xor(m, off));
            if (lane == 0) redM[rowg][wid & 3] = m;
            __syncthreads();                               // B2
            const float M = fmaxf(fmaxf(redM[rowg][0], redM[rowg][1]),
                                  fmaxf(redM[rowg][2], redM[rowg][3]));
            const float ea = __expf(za - M);
            p_s[rowg][jg] = ea;
            float eb = 0.f;
            if (jg < 64) { eb = __expf(zb - M); p_s[rowg][256 + jg] = eb; }
            float sa = ea + eb;
            float sh = (jg >= 44 && jg < 64) ? eb : 0.f;   // l in [300,320)
            #pragma unroll
            for (int off = 32; off > 0; off >>= 1) { sa += __shfl_xor(sa, off); sh += __shfl_xor(sh, off); }
            if (lane == 0) { redS[rowg][wid & 3][0] = sa; redS[rowg][wid & 3][1] = sh; }
        }
        __syncthreads();                                   // B3

        // ---- vocab binning (home rows) ----
        if (jg < NV) {
            const int o0 = offs16[rowg][jg], o1 = offs16[rowg][jg + 1];
            float s = 0.f;
            for (int o = o0; o < o1; ++o) s += p_s[rowg][idx16[rowg][o]];
            cw_s[rowg][jg] = s;
        }
        __syncthreads();                                   // B4

        // ---- phase 2: x for home rows -> publish to xex ----
        {
            const int j = q4;
            const float SA  = redS[r4][0][0] + redS[r4][1][0] + redS[r4][2][0] + redS[r4][3][0];
            const float SH  = redS[r4][0][1] + redS[r4][1][1] + redS[r4][2][1] + redS[r4][3][1];
            const float inv = 1.0f / SA;
            const float s300 = SA - SH;
            float acc = s300 * Q2PE[j];
            const float* __restrict__ cwr = cw_s[r4];
            #pragma unroll 5
            for (int vb = 0; vb < 20; ++vb) {
                const float4 qv = *(const float4*)(Q2TP + vb * 1024 + j * 4);
                const float4 cv = *(const float4*)(cwr + vb * 4);
                acc += qv.x * cv.x + qv.y * cv.y + qv.z * cv.z + qv.w * cv.w;
            }
            acc += cwr[80] * Q2TP[20 * 1024 + j * 4];
            const int xv = xd_s[r4];
            xex[(size_t)(grow0 + r4) * NH + j] = (f16)fmaxf(P2B[xv * NH + j] + acc * inv, 0.f);
        }
        __syncthreads();                                   // B5 (x writes complete)
        if (tid == 0) {
            __threadfence();
            __hip_atomic_store(&fx[cs * 16], t + 1, __ATOMIC_RELEASE, __HIP_MEMORY_SCOPE_AGENT);
        }

        // ---- gates h-half MFMA (waves 0-7) overlapped with x-spin (wave 8) ----
        f32x4 ga0 = {0.f,0.f,0.f,0.f}, ga1 = {0.f,0.f,0.f,0.f};
        if (wid < 8) {
            const f16* __restrict__ B = WCATM + (size_t)(cs * 8 + wid) * 8192 + lane * 8;
            #pragma unroll 4
            for (int kw = 8; kw < 16; ++kw) {
                const f16x8 b = *(const f16x8*)(B + kw * 512);
                const f16x8 a0 = *(const f16x8*)(&hbufh[mrow][khi * 8 + (kw - 8) * 32]);
                const f16x8 a1 = *(const f16x8*)(&hbufh[16 + mrow][khi * 8 + (kw - 8) * 32]);
                ga0 = __builtin_amdgcn_mfma_f32_16x16x32_f16(a0, b, ga0, 0, 0, 0);
                ga1 = __builtin_amdgcn_mfma_f32_16x16x32_f16(a1, b, ga1, 0, 0, 0);
            }
        } else if (wid == 8 && lane < 8 && lane != cs) {
            while (__hip_atomic_load(&fx[lane * 16], __ATOMIC_ACQUIRE, __HIP_MEMORY_SCOPE_AGENT) < t + 1)
                __builtin_amdgcn_s_sleep(4);
        }
        __syncthreads();                                   // B6 (x exchange visible)

        // ---- assemble xh[32][256] from xex ----
        {
            const int rr = tid >> 5, c8 = (tid & 31) * 8;
            *(f16x8*)(&xh[rr][c8]) = *(const f16x8*)(xex + (size_t)(rbase + rr) * NH + c8);
        }
        __syncthreads();                                   // B7

        // ---- gates x-half MFMA + write gex ----
        if (wid < 8) {
            const f16* __restrict__ B = WCATM + (size_t)(cs * 8 + wid) * 8192 + lane * 8;
            #pragma unroll 4
            for (int kw = 0; kw < 8; ++kw) {
                const f16x8 b = *(const f16x8*)(B + kw * 512);
                const f16x8 a0 = *(const f16x8*)(&xh[mrow][khi * 8 + kw * 32]);
                const f16x8 a1 = *(const f16x8*)(&xh[16 + mrow][khi * 8 + kw * 32]);
                ga0 = __builtin_amdgcn_mfma_f32_16x16x32_f16(a0, b, ga0, 0, 0, 0);
                ga1 = __builtin_amdgcn_mfma_f32_16x16x32_f16(a1, b, ga1, 0, 0, 0);
            }
            const int cc = wid * 16 + mrow;
            #pragma unroll
            for (int i = 0; i < 4; ++i) {
                gex[khi * 4 + i][cc]      = ga0[i];
                gex[16 + khi * 4 + i][cc] = ga1[i];
            }
        }
        __syncthreads();                                   // B8

        // ---- LSTM pointwise for (32 rows x my 32 units) -> publish h ----
        {
            const int r = tid >> 5, u = tid & 31;
            const float4 g4 = *(const float4*)(&gex[r][u * 4]);   // i,f,g,o
            const float4 b4 = *(const float4*)(bsum_lds + u * 4);
            creg = sigm(g4.y + b4.y) * creg + sigm(g4.x + b4.x) * tanhf_(g4.z + b4.z);
            hex[(size_t)(rbase + r) * NH + cs * 32 + u] = (f16)(sigm(g4.w + b4.w) * tanhf_(creg));
        }
        __syncthreads();                                   // B9 (h writes complete)
        if (tid == 0) {
            __threadfence();
            __hip_atomic_store(&fh[cs * 16], t + 1, __ATOMIC_RELEASE, __HIP_MEMORY_SCOPE_AGENT);
        }
        if (wid == 8 && lane < 8 && lane != cs) {
            while (__hip_atomic_load(&fh[lane * 16], __ATOMIC_ACQUIRE, __HIP_MEMORY_SCOPE_AGENT) < t + 1)
                __builtin_amdgcn_s_sleep(4);
        }
        __syncthreads();                                   // B10 (h exchange visible)

        // ---- assemble hbufh[32][256] from hex ----
        {
            const int rr = tid >> 5, c8 = (tid & 31) * 8;
            *(f16x8*)(&hbufh[rr][c8]) = *(const f16x8*)(hex + (size_t)(rbase + rr) * NH + c8);
        }
        __syncthreads();                                   // B11

        // ---- phase 4: fc logits for home rows (fp16 dot2, k-split x2) ----
        if (q4 < 2 * NV) {
            const int v  = (q4 < NV) ? q4 : q4 - NV;
            const int ks = (q4 >= NV) ? 1 : 0;
            const f16* __restrict__ hr = &hbufh[home0 + r4][ks * 128];
            const f16* __restrict__ wp = WFCPH + (ks * 16) * 648 + v * 8;
            float acc = 0.f;
            #pragma unroll 4
            for (int kb = 0; kb < 16; ++kb) {
                const float4 w  = *(const float4*)(wp + kb * 648);
                const float4 h4 = *(const float4*)(hr + kb * 8);
                DOT4(w, h4, acc);
            }
            lgpart[ks][r4][v] = acc;
        }
        __syncthreads();                                   // B12
        if (tid < 4 * NV) {
            const int rr = tid / NV, v = tid - rr * NV;
            const float lv = lgpart[0][rr][v] + lgpart[1][rr][v] + bfc_s[v];
            lg_s[rr][v] = lv;
            out_logits[((size_t)t * NB + grow0 + rr) * NV + v] = lv;
        }
        __syncthreads();                                   // B13

        // ---- argmax (first-max) + loss, one wave per home row ----
        if (wid < 4) {
            const int rr = wid;
            float v0 = lg_s[rr][lane]; int i0 = lane;
            if (lane < NV - 64) {
                const float vb = lg_s[rr][64 + lane];
                if (vb > v0) { v0 = vb; i0 = 64 + lane; }
            }
            #pragma unroll
            for (int off = 32; off > 0; off >>= 1) {
                const float vo = __shfl_xor(v0, off);
                const int   io = __shfl_xor(i0, off);
                if (vo > v0 || (vo == v0 && io < i0)) { v0 = vo; i0 = io; }
            }
            float e = __expf(lg_s[rr][lane] - v0);
            if (lane < NV - 64) e += __expf(lg_s[rr][64 + lane] - v0);
            #pragma unroll
            for (int off = 32; off > 0; off >>= 1) e += __shfl_xor(e, off);
            if (lane == 0) {
                const int y = tgt[(grow0 + rr) * NT + t];
                loss_s[rr] += -(lg_s[rr][y] - v0 - logf(e));
                xd_s[rr] = i0;
            }
        }
        __syncthreads();                                   // B14
    }

    if (tid < 4) loss_out[grow0 + tid] = loss_s[tid];
}

// ---------------- final mean ----------------
__global__ __launch_bounds__(256) void k_final(const float* __restrict__ loss, float* __restrict__ dst) {
    const int tid = threadIdx.x;
    float v = loss[tid] + loss[tid + 256] + loss[tid + 512] + loss[tid + 768];
    #pragma unroll
    for (int o = 32; o > 0; o >>= 1) v += __shfl_xor(v, o);
    __shared__ float red[4];
    if ((tid & 63) == 0) red[tid >> 6] = v;
    __syncthreads();
    if (tid == 0) dst[0] = (red[0] + red[1] + red[2] + red[3]) / (float)(NB * NT);
}

extern "C" void kernel_launch(void* const* d_in, const int* in_sizes, int n_in,
                              void* d_out, int out_size, void* d_ws, size_t ws_size,
                              hipStream_t stream) {
    const int*   enc    = (const int*)d_in[0];
    const int*   tgt    = (const int*)d_in[1];
    const float* emb    = (const float*)d_in[3];
    const float* W_att  = (const float*)d_in[4];
    const float* b_att  = (const float*)d_in[5];
    const float* W_comb = (const float*)d_in[6];
    const float* b_comb = (const float*)d_in[7];
    const float* W_ih   = (const float*)d_in[8];
    const float* b_ih   = (const float*)d_in[9];
    const float* W_hh   = (const float*)d_in[10];
    const float* b_hh   = (const float*)d_in[11];
    const float* W_fc   = (const float*)d_in[12];
    const float* b_fc   = (const float*)d_in[13];

    float* ws  = (float*)d_ws;
    float* out = (float*)d_out;
    f16* WCATM = (f16*)(ws + OFF_WCATM);
    f16* WATTM = (f16*)(ws + OFF_WATTM);
    f16* WFCPH = (f16*)(ws + OFF_WFCPH);
    f16* XEX   = (f16*)(ws + OFF_XEX);
    f16* HEX   = (f16*)(ws + OFF_HEX);
    int* FLAGX = (int*)(ws + OFF_FLAG);
    int* FLAGH = FLAGX + 4096;

    hipLaunchKernelGGL(k_pe,      dim3(1),    dim3(128), 0, stream, ws + OFF_PE);
    hipLaunchKernelGGL(k_tr_att,  dim3(640),  dim3(256), 0, stream, W_att,  ws + OFF_WATT);
    hipLaunchKernelGGL(k_tr_comb, dim3(512),  dim3(256), 0, stream, W_comb, ws + OFF_WCOMBT);
    hipLaunchKernelGGL(k_p1b,     dim3(81),   dim3(320), 0, stream, emb, ws + OFF_WATT, b_att, ws + OFF_P1B);
    hipLaunchKernelGGL(k_p2q,     dim3(81),   dim3(256), 0, stream, emb, ws + OFF_WCOMBT, b_comb,
                       ws + OFF_P2B, ws + OFF_Q2T);
    hipLaunchKernelGGL(k_q2pe,    dim3(1),    dim3(256), 0, stream, ws + OFF_PE, ws + OFF_WCOMBT, ws + OFF_Q2PE);
    hipLaunchKernelGGL(k_pan_q2,  dim3(81),   dim3(256), 0, stream, ws + OFF_Q2T, ws + OFF_Q2TP);
    hipLaunchKernelGGL(k_pan_cat_m, dim3(2048), dim3(256), 0, stream, W_ih, W_hh, WCATM);
    hipLaunchKernelGGL(k_pan_att_m, dim3(320),  dim3(256), 0, stream, W_att, WATTM);
    hipLaunchKernelGGL(k_pan_fc_h,  dim3(81),   dim3(256), 0, stream, W_fc, WFCPH);
    hipLaunchKernelGGL(k_zero,      dim3(32),   dim3(256), 0, stream, FLAGX);

    hipLaunchKernelGGL(k_run, dim3(256), dim3(1024), 0, stream,
                       enc, tgt,
                       WATTM, ws + OFF_P1B, ws + OFF_P2B,
                       ws + OFF_Q2TP, ws + OFF_Q2PE, WCATM, WFCPH,
                       b_ih, b_hh, b_fc, XEX, HEX, FLAGX, FLAGH,
                       out, ws + OFF_LOSS);

    hipLaunchKernelGGL(k_final, dim3(1), dim3(256), 0, stream, ws + OFF_LOSS, out + (out_size - 1));
}

// Round 9
// 2758.841 us; speedup vs baseline: 2.0645x; 2.0645x over previous
//
#include <hip/hip_runtime.h>

#define NB 1024
#define SL 300
#define NT 150
#define NH 256
#define LA 320
#define NV 81
#define HST 272   // f16 row stride: 136 words; A-frag chunk slots uniform 2-way -> conflict-free

typedef _Float16 f16;
typedef _Float16 f16x2 __attribute__((ext_vector_type(2)));
typedef _Float16 f16x8 __attribute__((ext_vector_type(8)));
typedef float    f32x4 __attribute__((ext_vector_type(4)));

// ws float offsets (round-6 layouts)
#define OFF_WATT    0u
#define OFF_WCOMBT  163840u
#define OFF_P1B     294912u
#define OFF_P2B     320832u
#define OFF_Q2T     341568u
#define OFF_Q2PE    362304u
#define OFF_PE      362560u
#define OFF_Q2TP    362816u
#define OFF_WCATM   384320u    // f16 [64 nt][16 kw][64 lane][8]
#define OFF_WATTM   646464u    // f16 [20 nt][8 kw][64 lane][8]
#define OFF_WFCPH   687424u    // f16 [32][81][8]
#define OFF_LOSS    697792u

static __device__ __forceinline__ float rcpf(float x)  { return __builtin_amdgcn_rcpf(x); }
static __device__ __forceinline__ float sigm(float x)  { return rcpf(1.f + __expf(-x)); }
static __device__ __forceinline__ float tanhf_(float x){ return 1.f - 2.f * rcpf(1.f + __expf(2.f * x)); }

static __device__ __forceinline__ float dot2(f16x2 a, f16x2 b, float c) {
#if __has_builtin(__builtin_amdgcn_fdot2)
    return __builtin_amdgcn_fdot2(a, b, c, false);
#else
    return c + (float)a[0] * (float)b[0] + (float)a[1] * (float)b[1];
#endif
}
#define DOT4(wf4, af4, acc) { \
    acc = dot2(__builtin_bit_cast(f16x2, (wf4).x), __builtin_bit_cast(f16x2, (af4).x), acc); \
    acc = dot2(__builtin_bit_cast(f16x2, (wf4).y), __builtin_bit_cast(f16x2, (af4).y), acc); \
    acc = dot2(__builtin_bit_cast(f16x2, (wf4).z), __builtin_bit_cast(f16x2, (af4).z), acc); \
    acc = dot2(__builtin_bit_cast(f16x2, (wf4).w), __builtin_bit_cast(f16x2, (af4).w), acc); }

static __device__ __forceinline__ void ctr_add(int* p) {
    if ((threadIdx.x & 63) == 0)
        __hip_atomic_fetch_add(p, 1, __ATOMIC_RELEASE, __HIP_MEMORY_SCOPE_WORKGROUP);
}
static __device__ __forceinline__ void ctr_spin(int* p, int target) {
    while (__hip_atomic_load(p, __ATOMIC_ACQUIRE, __HIP_MEMORY_SCOPE_WORKGROUP) < target)
        __builtin_amdgcn_s_sleep(1);
}

// ---------------- setup kernels (unchanged) ----------------
__global__ __launch_bounds__(128) void k_pe(float* __restrict__ pe) {
    const int i = threadIdx.x;
    const float arg  = (float)(2 * i) * (-0.035977892078031968f);
    const float divf = expf(arg) * 300.0f;
    pe[2 * i]     = (float)sin((double)divf);
    pe[2 * i + 1] = (float)cos((double)divf);
}
__global__ __launch_bounds__(256) void k_tr_att(const float* __restrict__ W, float* __restrict__ WT) {
    const int i = blockIdx.x * 256 + threadIdx.x;
    if (i < 512 * LA) { const int k = i / LA, l = i - k * LA; WT[i] = W[l * 512 + k]; }
}
__global__ __launch_bounds__(256) void k_tr_comb(const float* __restrict__ W, float* __restrict__ WT) {
    const int i = blockIdx.x * 256 + threadIdx.x;
    const int k = i >> 8, j = i & 255;
    if (i < 512 * NH) WT[i] = W[j * 512 + k];
}
__global__ __launch_bounds__(320) void k_p1b(const float* __restrict__ emb, const float* __restrict__ WATT,
                                             const float* __restrict__ b_att, float* __restrict__ P1B) {
    __shared__ float e[NH];
    const int v = blockIdx.x, tid = threadIdx.x;
    if (tid < NH) e[tid] = emb[v * NH + tid];
    __syncthreads();
    float a = b_att[tid];
    #pragma unroll 8
    for (int k = 0; k < NH; ++k) a += e[k] * WATT[k * LA + tid];
    P1B[v * LA + tid] = a;
}
__global__ __launch_bounds__(256) void k_p2q(const float* __restrict__ emb, const float* __restrict__ WCOMBT,
                                             const float* __restrict__ b_comb,
                                             float* __restrict__ P2B, float* __restrict__ Q2T) {
    __shared__ float e[NH];
    const int v = blockIdx.x, tid = threadIdx.x;
    e[tid] = emb[v * NH + tid];
    __syncthreads();
    float a = b_comb[tid], q = 0.f;
    #pragma unroll 8
    for (int k = 0; k < NH; ++k) {
        a += e[k] * WCOMBT[k * NH + tid];
        q += e[k] * WCOMBT[(NH + k) * NH + tid];
    }
    P2B[v * NH + tid] = a;
    Q2T[v * NH + tid] = q;
}
__global__ __launch_bounds__(256) void k_q2pe(const float* __restrict__ pe, const float* __restrict__ WCOMBT,
                                              float* __restrict__ Q2PE) {
    __shared__ float e[NH];
    const int tid = threadIdx.x;
    e[tid] = pe[tid];
    __syncthreads();
    float q = 0.f;
    #pragma unroll 8
    for (int k = 0; k < NH; ++k) q += e[k] * WCOMBT[(NH + k) * NH + tid];
    Q2PE[tid] = q;
}
__global__ __launch_bounds__(256) void k_pan_q2(const float* __restrict__ Q2T, float* __restrict__ P) {
    const int i = blockIdx.x * 256 + threadIdx.x;
    if (i < NV * NH) {
        const int v = i >> 8, j = i & 255;
        P[(v >> 2) * 1024 + j * 4 + (v & 3)] = Q2T[v * NH + j];
    }
}
__global__ __launch_bounds__(256) void k_pan_cat_m(const float* __restrict__ Wih, const float* __restrict__ Whh,
                                                   f16* __restrict__ P) {
    const int i = blockIdx.x * 256 + threadIdx.x;
    if (i < 512 * 1024) {
        const int k = i >> 10, c = i & 1023, jcol = c >> 2, g = c & 3;
        const float v = (k < NH) ? Wih[(g * NH + jcol) * NH + k] : Whh[(g * NH + jcol) * NH + (k - NH)];
        const int nt = c >> 4, kw = k >> 5, kr = k & 31;
        const int l = (kr >> 3) * 16 + (c & 15), jj = kr & 7;
        P[nt * 8192 + kw * 512 + l * 8 + jj] = (f16)v;
    }
}
__global__ __launch_bounds__(256) void k_pan_att_m(const float* __restrict__ W, f16* __restrict__ P) {
    const int i = blockIdx.x * 256 + threadIdx.x;
    if (i < 256 * LA) {
        const int k = i / LA, lcol = i - k * LA;
        const float v = W[lcol * 512 + 256 + k];
        const int nt = lcol >> 4, kw = k >> 5, kr = k & 31;
        const int l = (kr >> 3) * 16 + (lcol & 15), jj = kr & 7;
        P[nt * 4096 + kw * 512 + l * 8 + jj] = (f16)v;
    }
}
__global__ __launch_bounds__(256) void k_pan_fc_h(const float* __restrict__ W, f16* __restrict__ P) {
    const int i = blockIdx.x * 256 + threadIdx.x;
    if (i < 256 * NV) {
        const int k = i / NV, v = i - k * NV;
        P[(k >> 3) * 648 + v * 8 + (k & 7)] = (f16)W[v * NH + k];
    }
}

// ---------------- persistent decoder: 256 blocks x 1024 thr, 4 rows/block, wave-specialized ----------------
__global__ __launch_bounds__(1024, 4) void k_run(
    const int* __restrict__ enc, const int* __restrict__ tgt,
    const f16* __restrict__ WATTM, const float* __restrict__ P1B,
    const float* __restrict__ P2B, const float* __restrict__ Q2TP,
    const float* __restrict__ Q2PE, const f16* __restrict__ WCATM,
    const f16* __restrict__ WFCPH,
    const float* __restrict__ bih, const float* __restrict__ bhh,
    const float* __restrict__ bfc, float* __restrict__ out_logits,
    float* __restrict__ loss_out)
{
    __shared__ __attribute__((aligned(16))) f16 hbufh[2][4][HST];
    __shared__ __attribute__((aligned(16))) f16 xh[4][HST];
    __shared__ float p_s[4][324];
    __shared__ float gex[4][1040];
    __shared__ float bsum_lds[1024];
    __shared__ float cw_s[4][84];
    __shared__ float lg_s[4][84];
    __shared__ float sm_inv[4], sm_s300[4];
    __shared__ unsigned short idx16[4][SL];
    __shared__ unsigned short cnt16[4][NV];
    __shared__ unsigned short offs16[4][NV + 1];
    __shared__ float bfc_s[84];
    __shared__ float loss_s[4];
    __shared__ int   xd_s[4];
    __shared__ int   c_aP1, c_aSM, c_xr, c_gd, c_hr;

    const int tid  = threadIdx.x;
    const int rowg = tid >> 8;
    const int jg   = tid & 255;
    const int wid  = tid >> 6;
    const int lane = tid & 63;
    const int mrow = lane & 15;
    const int arow4 = mrow & 3;
    const int khi  = lane >> 4;
    const int row0 = blockIdx.x * 4;

    // ---- init (one-time; __syncthreads allowed here) ----
    for (int i = tid; i < 2 * 4 * HST; i += 1024) {
        const int b = i / (4 * HST), r = (i / HST) & 3, c = i % HST;
        hbufh[b][r][c] = (f16)0.f;
    }
    { const int c = tid, j = c >> 2, g = c & 3; bsum_lds[c] = bih[g * NH + j] + bhh[g * NH + j]; }
    if (tid < 84) bfc_s[tid] = (tid < NV) ? bfc[tid] : 0.f;
    if (tid < 4) { xd_s[tid] = 1; loss_s[tid] = 0.f; }
    if (tid < 4 * 84) cw_s[tid / 84][tid % 84] = 0.f;
    if (tid == 0) { c_aP1 = 0; c_aSM = 0; c_xr = 0; c_gd = 0; c_hr = 0; }
    const int* __restrict__ encr = enc + (row0 + rowg) * SL;
    if (jg < NV) {
        int c = 0;
        for (int l = 0; l < SL; ++l) c += (encr[l] == jg);
        cnt16[rowg][jg] = (unsigned short)c;
    }
    __syncthreads();
    if (jg == 0) {
        int o = 0; offs16[rowg][0] = 0;
        for (int v = 0; v < NV; ++v) { o += cnt16[rowg][v]; offs16[rowg][v + 1] = (unsigned short)o; }
    }
    __syncthreads();
    if (jg < NV) {
        int o = offs16[rowg][jg];
        for (int l = 0; l < SL; ++l) if (encr[l] == jg) idx16[rowg][o++] = (unsigned short)l;
    }
    __syncthreads();

    if (wid >= 8) {
        // ================= GATES WAVES (wid 8..15): stream B, MFMA both halves =================
        const int nt0 = (wid - 8) * 8;
        for (int t = 0; t < NT; ++t) {
            const int pb = t & 1;
            ctr_spin(&c_hr, 8 * t);                        // h(t) ready (t=0 trivial)
            f32x4 acc[8];
            #pragma unroll
            for (int i = 0; i < 8; ++i) acc[i] = (f32x4){0.f, 0.f, 0.f, 0.f};
            {   // h-half: kw 8..15  (A element index = k - 256 = (kw-8)*32 + khi*8 + jj)
                const f16* __restrict__ hr = &hbufh[pb][arow4][khi * 8];
                const f16* __restrict__ B  = WCATM + (size_t)nt0 * 8192 + lane * 8;
                #pragma unroll 2
                for (int kw = 8; kw < 16; ++kw) {
                    const f16x8 a = *(const f16x8*)(hr + (kw - 8) * 32);
                    const f16* bp = B + kw * 512;
                    #pragma unroll
                    for (int i = 0; i < 8; ++i)
                        acc[i] = __builtin_amdgcn_mfma_f32_16x16x32_f16(
                            a, *(const f16x8*)(bp + (size_t)i * 8192), acc[i], 0, 0, 0);
                }
            }
            ctr_spin(&c_xr, 8 * (t + 1));                  // x(t) published
            {   // x-half: kw 0..7
                const f16* __restrict__ xr = &xh[arow4][khi * 8];
                const f16* __restrict__ B  = WCATM + (size_t)nt0 * 8192 + lane * 8;
                #pragma unroll 2
                for (int kw = 0; kw < 8; ++kw) {
                    const f16x8 a = *(const f16x8*)(xr + kw * 32);
                    const f16* bp = B + kw * 512;
                    #pragma unroll
                    for (int i = 0; i < 8; ++i)
                        acc[i] = __builtin_amdgcn_mfma_f32_16x16x32_f16(
                            a, *(const f16x8*)(bp + (size_t)i * 8192), acc[i], 0, 0, 0);
                }
            }
            if (lane < 16) {
                #pragma unroll
                for (int i = 0; i < 8; ++i) {
                    const int cc = (nt0 + i) * 16 + mrow;
                    #pragma unroll
                    for (int j = 0; j < 4; ++j) gex[j][cc] = acc[i][j];
                }
            }
            ctr_add(&c_gd);
        }
    } else {
        // ================= ATTENTION / VALU WAVES (wid 0..7) =================
        const int w = wid;
        float creg0 = 0.f, creg1 = 0.f;    // (r=tid>>8, u) and (r+2, u)
        for (int t = 0; t < NT; ++t) {
            const int pb = t & 1;
            ctr_spin(&c_hr, 8 * t);                        // all LSTM(t-1) writes visible
            // ---- P1: attention MFMA, wave w owns nt {w, w+8, (+w+16 if w<4)} ----
            {
                f32x4 z0 = {0.f,0.f,0.f,0.f}, z1 = {0.f,0.f,0.f,0.f}, z2 = {0.f,0.f,0.f,0.f};
                const bool three = (w < 4);
                const f16* __restrict__ B0 = WATTM + w * 4096 + lane * 8;
                const f16* __restrict__ B1 = WATTM + (8 + w) * 4096 + lane * 8;
                const f16* __restrict__ B2 = WATTM + (16 + w) * 4096 + lane * 8;
                const f16* __restrict__ hr = &hbufh[pb][arow4][khi * 8];
                #pragma unroll 2
                for (int kw = 0; kw < 8; ++kw) {
                    const f16x8 a = *(const f16x8*)(hr + kw * 32);
                    z0 = __builtin_amdgcn_mfma_f32_16x16x32_f16(a, *(const f16x8*)(B0 + kw * 512), z0, 0, 0, 0);
                    z1 = __builtin_amdgcn_mfma_f32_16x16x32_f16(a, *(const f16x8*)(B1 + kw * 512), z1, 0, 0, 0);
                    if (three)
                        z2 = __builtin_amdgcn_mfma_f32_16x16x32_f16(a, *(const f16x8*)(B2 + kw * 512), z2, 0, 0, 0);
                }
                if (lane < 16) {
                    #pragma unroll
                    for (int i = 0; i < 4; ++i) {
                        p_s[i][w * 16 + mrow]       = z0[i];
                        p_s[i][(8 + w) * 16 + mrow] = z1[i];
                        if (three) p_s[i][(16 + w) * 16 + mrow] = z2[i];
                    }
                }
            }
            ctr_add(&c_aP1);
            // ---- softmax + binning: one wave per row (waves 0-3) ----
            if (w < 4) {
                ctr_spin(&c_aP1, 8 * (t + 1));
                const int r = w;
                const float* __restrict__ P1r = P1B + xd_s[r] * LA;
                float zv[5];
                #pragma unroll
                for (int i = 0; i < 5; ++i) zv[i] = p_s[r][lane + 64 * i] + P1r[lane + 64 * i];
                float m = fmaxf(fmaxf(fmaxf(zv[0], zv[1]), fmaxf(zv[2], zv[3])), zv[4]);
                #pragma unroll
                for (int off = 32; off > 0; off >>= 1) m = fmaxf(m, __shfl_xor(m, off));
                float sa = 0.f;
                #pragma unroll
                for (int i = 0; i < 5; ++i) {
                    zv[i] = __expf(zv[i] - m);
                    p_s[r][lane + 64 * i] = zv[i];
                    sa += zv[i];
                }
                float sh = (lane >= 44) ? zv[4] : 0.f;     // l in [300,320)
                #pragma unroll
                for (int off = 32; off > 0; off >>= 1) { sa += __shfl_xor(sa, off); sh += __shfl_xor(sh, off); }
                {   // bins 0..63
                    const int o0 = offs16[r][lane], o1 = offs16[r][lane + 1];
                    float s = 0.f;
                    for (int o = o0; o < o1; ++o) s += p_s[r][idx16[r][o]];
                    cw_s[r][lane] = s;
                }
                if (lane < NV - 64) {   // bins 64..80
                    const int b2 = 64 + lane;
                    const int o0 = offs16[r][b2], o1 = offs16[r][b2 + 1];
                    float s = 0.f;
                    for (int o = o0; o < o1; ++o) s += p_s[r][idx16[r][o]];
                    cw_s[r][b2] = s;
                }
                if (lane == 0) { sm_inv[r] = 1.0f / sa; sm_s300[r] = sa - sh; }
                ctr_add(&c_aSM);
            }
            ctr_spin(&c_aSM, 4 * (t + 1));
            // ---- phase 2: x (1024 items over 512 threads) ----
            #pragma unroll
            for (int half = 0; half < 2; ++half) {
                const int item = tid + half * 512;
                const int r = item >> 8, j = item & 255;
                const float inv = sm_inv[r], s300 = sm_s300[r];
                float acc = s300 * Q2PE[j];
                const float* __restrict__ cwr = cw_s[r];
                #pragma unroll 5
                for (int vb = 0; vb < 20; ++vb) {
                    const float4 qv = *(const float4*)(Q2TP + vb * 1024 + j * 4);
                    const float4 cv = *(const float4*)(cwr + vb * 4);
                    acc += qv.x * cv.x + qv.y * cv.y + qv.z * cv.z + qv.w * cv.w;
                }
                acc += cwr[80] * Q2TP[20 * 1024 + j * 4];
                xh[r][j] = (f16)fmaxf(P2B[xd_s[r] * NH + j] + acc * inv, 0.f);
            }
            ctr_add(&c_xr);
            // ---- LSTM pointwise (needs gates done) ----
            ctr_spin(&c_gd, 8 * (t + 1));
            {
                const int r0 = tid >> 8, u = tid & 255;
                const float4 g0 = *(const float4*)(&gex[r0][u * 4]);
                const float4 b4 = *(const float4*)(&bsum_lds[u * 4]);
                creg0 = sigm(g0.y + b4.y) * creg0 + sigm(g0.x + b4.x) * tanhf_(g0.z + b4.z);
                hbufh[pb ^ 1][r0][u] = (f16)(sigm(g0.w + b4.w) * tanhf_(creg0));
                const float4 g1 = *(const float4*)(&gex[r0 + 2][u * 4]);
                creg1 = sigm(g1.y + b4.y) * creg1 + sigm(g1.x + b4.x) * tanhf_(g1.z + b4.z);
                hbufh[pb ^ 1][r0 + 2][u] = (f16)(sigm(g1.w + b4.w) * tanhf_(creg1));
            }
            ctr_add(&c_hr);
            // ---- fc + argmax + loss: waves 0-3, one row each (overlaps gw h-half(t+1)) ----
            if (w < 4) {
                ctr_spin(&c_hr, 8 * (t + 1));
                const int r = w;
                const f16* __restrict__ hr = &hbufh[pb ^ 1][r][0];
                const int v1 = lane;
                float a1 = 0.f;
                {
                    const f16* __restrict__ wp = WFCPH + v1 * 8;
                    #pragma unroll 4
                    for (int kb = 0; kb < 32; ++kb) {
                        const float4 wv = *(const float4*)(wp + kb * 648);
                        const float4 hv = *(const float4*)(hr + kb * 8);
                        DOT4(wv, hv, a1);
                    }
                }
                const float lv1 = a1 + bfc_s[v1];
                if (v1 < NV) {
                    lg_s[r][v1] = lv1;
                    out_logits[((size_t)t * NB + row0 + r) * NV + v1] = lv1;
                }
                if (lane < NV - 64) {
                    const int v2 = 64 + lane;
                    float a2 = 0.f;
                    const f16* __restrict__ wp = WFCPH + v2 * 8;
                    #pragma unroll 4
                    for (int kb = 0; kb < 32; ++kb) {
                        const float4 wv = *(const float4*)(wp + kb * 648);
                        const float4 hv = *(const float4*)(hr + kb * 8);
                        DOT4(wv, hv, a2);
                    }
                    const float lv2 = a2 + bfc_s[v2];
                    lg_s[r][v2] = lv2;
                    out_logits[((size_t)t * NB + row0 + r) * NV + v2] = lv2;
                }
                // argmax (first-max) + loss within the wave
                float v0 = lg_s[r][lane]; int i0 = lane;
                if (lane < NV - 64) {
                    const float vb = lg_s[r][64 + lane];
                    if (vb > v0) { v0 = vb; i0 = 64 + lane; }
                }
                #pragma unroll
                for (int off = 32; off > 0; off >>= 1) {
                    const float vo = __shfl_xor(v0, off);
                    const int   io = __shfl_xor(i0, off);
                    if (vo > v0 || (vo == v0 && io < i0)) { v0 = vo; i0 = io; }
                }
                float e = __expf(lg_s[r][lane] - v0);
                if (lane < NV - 64) e += __expf(lg_s[r][64 + lane] - v0);
                #pragma unroll
                for (int off = 32; off > 0; off >>= 1) e += __shfl_xor(e, off);
                if (lane == 0) {
                    const int y = tgt[(row0 + r) * NT + t];
                    loss_s[r] += -(lg_s[r][y] - v0 - logf(e));
                    xd_s[r] = i0;
                }
            }
        }
        if (tid < 4) loss_out[row0 + tid] = loss_s[tid];
    }
}

// ---------------- final mean ----------------
__global__ __launch_bounds__(256) void k_final(const float* __restrict__ loss, float* __restrict__ dst) {
    const int tid = threadIdx.x;
    float v = loss[tid] + loss[tid + 256] + loss[tid + 512] + loss[tid + 768];
    #pragma unroll
    for (int o = 32; o > 0; o >>= 1) v += __shfl_xor(v, o);
    __shared__ float red[4];
    if ((tid & 63) == 0) red[tid >> 6] = v;
    __syncthreads();
    if (tid == 0) dst[0] = (red[0] + red[1] + red[2] + red[3]) / (float)(NB * NT);
}

extern "C" void kernel_launch(void* const* d_in, const int* in_sizes, int n_in,
                              void* d_out, int out_size, void* d_ws, size_t ws_size,
                              hipStream_t stream) {
    const int*   enc    = (const int*)d_in[0];
    const int*   tgt    = (const int*)d_in[1];
    const float* emb    = (const float*)d_in[3];
    const float* W_att  = (const float*)d_in[4];
    const float* b_att  = (const float*)d_in[5];
    const float* W_comb = (const float*)d_in[6];
    const float* b_comb = (const float*)d_in[7];
    const float* W_ih   = (const float*)d_in[8];
    const float* b_ih   = (const float*)d_in[9];
    const float* W_hh   = (const float*)d_in[10];
    const float* b_hh   = (const float*)d_in[11];
    const float* W_fc   = (const float*)d_in[12];
    const float* b_fc   = (const float*)d_in[13];

    float* ws  = (float*)d_ws;
    float* out = (float*)d_out;
    f16* WCATM = (f16*)(ws + OFF_WCATM);
    f16* WATTM = (f16*)(ws + OFF_WATTM);
    f16* WFCPH = (f16*)(ws + OFF_WFCPH);

    hipLaunchKernelGGL(k_pe,      dim3(1),    dim3(128), 0, stream, ws + OFF_PE);
    hipLaunchKernelGGL(k_tr_att,  dim3(640),  dim3(256), 0, stream, W_att,  ws + OFF_WATT);
    hipLaunchKernelGGL(k_tr_comb, dim3(512),  dim3(256), 0, stream, W_comb, ws + OFF_WCOMBT);
    hipLaunchKernelGGL(k_p1b,     dim3(81),   dim3(320), 0, stream, emb, ws + OFF_WATT, b_att, ws + OFF_P1B);
    hipLaunchKernelGGL(k_p2q,     dim3(81),   dim3(256), 0, stream, emb, ws + OFF_WCOMBT, b_comb,
                       ws + OFF_P2B, ws + OFF_Q2T);
    hipLaunchKernelGGL(k_q2pe,    dim3(1),    dim3(256), 0, stream, ws + OFF_PE, ws + OFF_WCOMBT, ws + OFF_Q2PE);
    hipLaunchKernelGGL(k_pan_q2,  dim3(81),   dim3(256), 0, stream, ws + OFF_Q2T, ws + OFF_Q2TP);
    hipLaunchKernelGGL(k_pan_cat_m, dim3(2048), dim3(256), 0, stream, W_ih, W_hh, WCATM);
    hipLaunchKernelGGL(k_pan_att_m, dim3(320),  dim3(256), 0, stream, W_att, WATTM);
    hipLaunchKernelGGL(k_pan_fc_h,  dim3(81),   dim3(256), 0, stream, W_fc, WFCPH);

    hipLaunchKernelGGL(k_run, dim3(256), dim3(1024), 0, stream,
                       enc, tgt,
                       WATTM, ws + OFF_P1B, ws + OFF_P2B,
                       ws + OFF_Q2TP, ws + OFF_Q2PE, WCATM, WFCPH,
                       b_ih, b_hh, b_fc,
                       out, ws + OFF_LOSS);

    hipLaunchKernelGGL(k_final, dim3(1), dim3(256), 0, stream, ws + OFF_LOSS, out + (out_size - 1));
}